// Round 5
// baseline (186.300 us; speedup 1.0000x reference)
//
#include <hip/hip_runtime.h>

// Problem constants (fixed by the reference setup):
// B=16, C=64, NC=12500, N=50000, K=8, E=NC*K=100000
#define BATCH  16
#define CHAN   64
#define NCLIQ  12500
#define NODES  50000
#define NEDGE  100000
#define NGRP   64                                  // 1024 bc / 16 per group
#define ELLW   16                                  // slots per node (P(deg>16) ~ 1e-10)

#define FILL_BLOCKS   ((NEDGE + 255) / 256)        // 391
#define PACK_BLOCKS_X ((NCLIQ + 255) / 256)        // 49
#define PACK_BLOCKS   (PACK_BLOCKS_X * NGRP)       // 3136

#define NODES_PER_BLK 256                          // 64 strips x 4 nodes
#define NBLKG ((NODES + NODES_PER_BLK - 1) / NODES_PER_BLK)   // 196

typedef float f32x4 __attribute__((ext_vector_type(4)));   // clang-native vec for NT stores

// ---------------- zero degree counters ----------------

__global__ __launch_bounds__(256) void zero_counts(int4* __restrict__ counts4) {
    int t = blockIdx.x * 256 + threadIdx.x;
    if (t < NODES / 4) counts4[t] = make_int4(0, 0, 0, 0);
}

// ---------------- fused: ELL build + 16-bc input pack (independent block ranges) ----
// blocks [0, FILL_BLOCKS): pos = atomic cursor per node; ell[n][pos] = clique.
// blocks [FILL_BLOCKS, ..): in[bc][col] -> inP[g][col][j], j = bc%16 (64B line/col).

__global__ __launch_bounds__(256) void fill_pack(const int* __restrict__ node_ids,
                                                 const int* __restrict__ clique_ids,
                                                 int* __restrict__ counts,
                                                 int* __restrict__ ell,
                                                 const float* __restrict__ in,
                                                 float* __restrict__ inP) {
    int b   = blockIdx.x;
    int tid = threadIdx.x;
    if (b < FILL_BLOCKS) {
        int e = b * 256 + tid;
        if (e < NEDGE) {
            int n   = node_ids[e];
            int pos = atomicAdd(&counts[n], 1);
            if (pos < ELLW) ell[(size_t)n * ELLW + pos] = clique_ids[e];
        }
    } else {
        int pb  = b - FILL_BLOCKS;
        int g   = pb / PACK_BLOCKS_X;
        int col = (pb % PACK_BLOCKS_X) * 256 + tid;
        if (col < NCLIQ) {
            float v[16];
            #pragma unroll
            for (int j = 0; j < 16; ++j)
                v[j] = __builtin_nontemporal_load(in + (size_t)(g * 16 + j) * NCLIQ + col);
            f32x4* dst = reinterpret_cast<f32x4*>(inP + ((size_t)g * NCLIQ + col) * 16);
            #pragma unroll
            for (int q = 0; q < 4; ++q) {
                f32x4 t4 = { v[4 * q], v[4 * q + 1], v[4 * q + 2], v[4 * q + 3] };
                __builtin_nontemporal_store(t4, dst + q);
            }
        }
    }
}

// ---------------- gather: thread = 4-node strip x 4-plane quad ----------------
// ELL int4 prefetch for 4 nodes breaks the index->data chain (up to 16 inP
// float4 loads in flight). 4 nontemporal f32x4 stores per thread, 256B
// contiguous per 16-lane group. XCD-phase decode keeps 8 inP slices (800KB
// each) L2-resident; ell+deg (3.4MB) L2/L3-resident across group passes.

__global__ __launch_bounds__(256) void gather_ell(const float* __restrict__ inP,
                                                  const int* __restrict__ deg,
                                                  const int* __restrict__ ell,
                                                  float* __restrict__ out) {
    int b     = blockIdx.x;
    int k     = b & 7;
    int r     = b >> 3;
    int nb    = r % NBLKG;
    int phase = r / NBLKG;
    int g     = phase * 8 + k;
    int tid   = threadIdx.x;
    int s     = tid >> 2;                       // node strip 0..63
    int q     = tid & 3;                        // plane quad 0..3
    int n0    = nb * NODES_PER_BLK + s * 4;
    if (n0 >= NODES) return;                    // NODES%4==0: strips all-or-nothing
    const float* __restrict__ gbase = inP + (size_t)g * NCLIQ * 16 + q * 4;

    int  dd[4];
    int4 e4[4];
    #pragma unroll
    for (int nn = 0; nn < 4; ++nn) {
        dd[nn] = deg[n0 + nn];
        e4[nn] = *reinterpret_cast<const int4*>(ell + (size_t)(n0 + nn) * ELLW);
    }

    float4 acc[4];
    #pragma unroll
    for (int nn = 0; nn < 4; ++nn) {
        acc[nn] = make_float4(0.f, 0.f, 0.f, 0.f);
        int d = dd[nn];
        int c[4] = { e4[nn].x, e4[nn].y, e4[nn].z, e4[nn].w };
        #pragma unroll
        for (int i = 0; i < 4; ++i) {
            if (i < d) {
                const float4 p = *reinterpret_cast<const float4*>(gbase + (size_t)c[i] * 16);
                acc[nn].x += p.x; acc[nn].y += p.y; acc[nn].z += p.z; acc[nn].w += p.w;
            }
        }
        if (d > 4) {                            // tail (P(deg>4) ~ 5%)
            for (int i = 4; i < d && i < ELLW; ++i) {
                int col = ell[(size_t)(n0 + nn) * ELLW + i];
                const float4 p = *reinterpret_cast<const float4*>(gbase + (size_t)col * 16);
                acc[nn].x += p.x; acc[nn].y += p.y; acc[nn].z += p.z; acc[nn].w += p.w;
            }
        }
    }

    size_t pbase = (size_t)(g * 16 + q * 4) * NODES + n0;
    f32x4 o0 = { acc[0].x, acc[1].x, acc[2].x, acc[3].x };
    f32x4 o1 = { acc[0].y, acc[1].y, acc[2].y, acc[3].y };
    f32x4 o2 = { acc[0].z, acc[1].z, acc[2].z, acc[3].z };
    f32x4 o3 = { acc[0].w, acc[1].w, acc[2].w, acc[3].w };
    __builtin_nontemporal_store(o0, reinterpret_cast<f32x4*>(out + pbase));
    __builtin_nontemporal_store(o1, reinterpret_cast<f32x4*>(out + pbase + NODES));
    __builtin_nontemporal_store(o2, reinterpret_cast<f32x4*>(out + pbase + 2 * (size_t)NODES));
    __builtin_nontemporal_store(o3, reinterpret_cast<f32x4*>(out + pbase + 3 * (size_t)NODES));
}

// ---------------- launch ----------------

extern "C" void kernel_launch(void* const* d_in, const int* in_sizes, int n_in,
                              void* d_out, int out_size, void* d_ws, size_t ws_size,
                              hipStream_t stream) {
    const float* in         = (const float*)d_in[0];
    const int*   node_ids   = (const int*)d_in[1];
    const int*   clique_ids = (const int*)d_in[2];
    float*       out        = (float*)d_out;

    // ws layout: counts[50000] | ell[50000*16] | inP[64*12500*16 floats]
    int*   counts = (int*)d_ws;
    int*   ell    = counts + NODES;                       // byte off 200,000
    float* inP    = (float*)(ell + (size_t)NODES * ELLW); // byte off 3,400,000 (16B-aligned)

    zero_counts<<<(NODES / 4 + 255) / 256, 256, 0, stream>>>((int4*)counts);
    fill_pack<<<FILL_BLOCKS + PACK_BLOCKS, 256, 0, stream>>>(node_ids, clique_ids,
                                                             counts, ell, in, inP);
    gather_ell<<<NGRP * NBLKG, 256, 0, stream>>>(inP, counts, ell, out);
}

// Round 6
// 182.167 us; speedup vs baseline: 1.0227x; 1.0227x over previous
//
#include <hip/hip_runtime.h>

// Problem constants (fixed by the reference setup):
// B=16, C=64, NC=12500, N=50000, K=8, E=NC*K=100000
#define BATCH  16
#define CHAN   64
#define NCLIQ  12500
#define NODES  50000
#define NEDGE  100000
#define NGRP   64                                  // 1024 bc / 16 per group
#define ELLW   16                                  // slots/node (dataset max deg <= 16, validated R5)

#define FILL_BLOCKS   ((NEDGE + 255) / 256)        // 391
#define PACK_BLOCKS_X ((NCLIQ + 255) / 256)        // 49
#define PACK_BLOCKS   (PACK_BLOCKS_X * NGRP)       // 3136

#define NODEB 64                                   // nodes per gather block
#define NBLK  ((NODES + NODEB - 1) / NODEB)        // 782

typedef float f32x4 __attribute__((ext_vector_type(4)));

// ---------------- zero degree counters ----------------

__global__ __launch_bounds__(256) void zero_counts(int4* __restrict__ counts4) {
    int t = blockIdx.x * 256 + threadIdx.x;
    if (t < NODES / 4) counts4[t] = make_int4(0, 0, 0, 0);
}

// ---------------- fused: ushort-ELL build + 16-bc input pack ----------------
// blocks [0, FILL_BLOCKS): pos = atomic cursor per node; ell16[n][pos] = clique.
// blocks [FILL_BLOCKS, ..): in[bc][col] -> inP[g][col][j], j = bc%16 (64B line/col).

__global__ __launch_bounds__(256) void fill_pack(const int* __restrict__ node_ids,
                                                 const int* __restrict__ clique_ids,
                                                 int* __restrict__ counts,
                                                 unsigned short* __restrict__ ell16,
                                                 const float* __restrict__ in,
                                                 float* __restrict__ inP) {
    int b   = blockIdx.x;
    int tid = threadIdx.x;
    if (b < FILL_BLOCKS) {
        int e = b * 256 + tid;
        if (e < NEDGE) {
            int n   = node_ids[e];
            int pos = atomicAdd(&counts[n], 1);
            if (pos < ELLW) ell16[(size_t)n * ELLW + pos] = (unsigned short)clique_ids[e];
        }
    } else {
        int pb  = b - FILL_BLOCKS;
        int g   = pb / PACK_BLOCKS_X;
        int col = (pb % PACK_BLOCKS_X) * 256 + tid;
        if (col < NCLIQ) {
            float v[16];
            #pragma unroll
            for (int j = 0; j < 16; ++j)
                v[j] = __builtin_nontemporal_load(in + (size_t)(g * 16 + j) * NCLIQ + col);
            f32x4* dst = reinterpret_cast<f32x4*>(inP + ((size_t)g * NCLIQ + col) * 16);
            #pragma unroll
            for (int q = 0; q < 4; ++q) {
                f32x4 t4 = { v[4 * q], v[4 * q + 1], v[4 * q + 2], v[4 * q + 3] };
                __builtin_nontemporal_store(t4, dst + q);
            }
        }
    }
}

// ---------------- gather: 1 node x 1 plane-quad per thread ----------------
// Wave = 16 nodes x 4 quads; the 4 q-lanes of a node read consecutive 16B of
// the same 64B inP line (full line use) and same-address ELL words (HW
// broadcast). 8 predicated uint4-decoded loads issued back-to-back -> 8
// outstanding per node, no serial col->load chain. Per-XCD working set:
// inP slice 800KB + ell16 1.6MB + deg 200KB = 2.6MB < 4MB L2.
// Output write-once -> nontemporal, keeps L2 for the gather working set.

__global__ __launch_bounds__(256) void gather_ell(const float* __restrict__ inP,
                                                  const int* __restrict__ deg,
                                                  const unsigned short* __restrict__ ell16,
                                                  float* __restrict__ out) {
    int b     = blockIdx.x;
    int k     = b & 7;
    int r     = b >> 3;
    int nb    = r % NBLK;
    int phase = r / NBLK;
    int g     = phase * 8 + k;                  // 8 groups active device-wide
    int tid   = threadIdx.x;
    int n     = nb * NODEB + (tid >> 2);
    int q     = tid & 3;
    if (n >= NODES) return;

    int d = deg[n];
    const uint4 e = *reinterpret_cast<const uint4*>(ell16 + (size_t)n * ELLW);
    unsigned cs[8] = { e.x & 0xFFFFu, e.x >> 16, e.y & 0xFFFFu, e.y >> 16,
                       e.z & 0xFFFFu, e.z >> 16, e.w & 0xFFFFu, e.w >> 16 };

    const float* __restrict__ gbase = inP + (size_t)g * NCLIQ * 16 + q * 4;
    float4 a  = make_float4(0.f, 0.f, 0.f, 0.f);
    float4 a2 = make_float4(0.f, 0.f, 0.f, 0.f);
    #pragma unroll
    for (int i = 0; i < 8; i += 2) {
        if (i < d) {
            const float4 p = *reinterpret_cast<const float4*>(gbase + (size_t)cs[i] * 16);
            a.x += p.x; a.y += p.y; a.z += p.z; a.w += p.w;
        }
        if (i + 1 < d) {
            const float4 p = *reinterpret_cast<const float4*>(gbase + (size_t)cs[i + 1] * 16);
            a2.x += p.x; a2.y += p.y; a2.z += p.z; a2.w += p.w;
        }
    }
    if (d > 8) {                                // P(deg>8) ~ 0.1%: scalar tail
        for (int i = 8; i < d && i < ELLW; ++i) {
            unsigned col = ell16[(size_t)n * ELLW + i];
            const float4 p = *reinterpret_cast<const float4*>(gbase + (size_t)col * 16);
            a.x += p.x; a.y += p.y; a.z += p.z; a.w += p.w;
        }
    }
    a.x += a2.x; a.y += a2.y; a.z += a2.z; a.w += a2.w;

    size_t base = (size_t)(g * 16 + q * 4) * NODES + n;
    __builtin_nontemporal_store(a.x, out + base);
    __builtin_nontemporal_store(a.y, out + base + NODES);
    __builtin_nontemporal_store(a.z, out + base + 2 * (size_t)NODES);
    __builtin_nontemporal_store(a.w, out + base + 3 * (size_t)NODES);
}

// ---------------- launch ----------------

extern "C" void kernel_launch(void* const* d_in, const int* in_sizes, int n_in,
                              void* d_out, int out_size, void* d_ws, size_t ws_size,
                              hipStream_t stream) {
    const float* in         = (const float*)d_in[0];
    const int*   node_ids   = (const int*)d_in[1];
    const int*   clique_ids = (const int*)d_in[2];
    float*       out        = (float*)d_out;

    // ws layout: counts[50000] int | ell16[50000*16] ushort | inP[64*12500*16] float
    int*            counts = (int*)d_ws;
    unsigned short* ell16  = (unsigned short*)(counts + NODES);          // byte 200,000
    float*          inP    = (float*)((char*)d_ws + 200000 + 1600000);   // byte 1,800,000 (16B-aligned)

    zero_counts<<<(NODES / 4 + 255) / 256, 256, 0, stream>>>((int4*)counts);
    fill_pack<<<FILL_BLOCKS + PACK_BLOCKS, 256, 0, stream>>>(node_ids, clique_ids,
                                                             counts, ell16, in, inP);
    gather_ell<<<NGRP * NBLK, 256, 0, stream>>>(inP, counts, ell16, out);
}

// Round 7
// 104.351 us; speedup vs baseline: 1.7853x; 1.7457x over previous
//
#include <hip/hip_runtime.h>

// Problem constants (fixed by the reference setup):
// B=16, C=64, NC=12500, N=50000, K=8, E=NC*K=100000
#define NCLIQ  12500
#define NODES  50000
#define NEDGE  100000
#define NGRP   64                                  // 1024 bc / 16 per group
#define ELLW   16                                  // slots/node

#define FILL_BLOCKS   ((NEDGE + 255) / 256)        // 391
#define COL4          (NCLIQ / 4)                  // 3125 (NCLIQ % 4 == 0)
#define PACK_BLOCKS_X ((COL4 + 255) / 256)         // 13
#define PACK_BLOCKS   (PACK_BLOCKS_X * NGRP)       // 832

#define NODEB 64                                   // nodes per gather block
#define NBLK  ((NODES + NODEB - 1) / NODEB)        // 782

typedef float f32x4 __attribute__((ext_vector_type(4)));

// ---------------- zero degree counters ----------------

__global__ __launch_bounds__(256) void zero_counts(int4* __restrict__ counts4) {
    int t = blockIdx.x * 256 + threadIdx.x;
    if (t < NODES / 4) counts4[t] = make_int4(0, 0, 0, 0);
}

// ---------------- fused: ushort-ELL build + 16-bc input pack ----------------
// blocks [0, FILL_BLOCKS): pos = atomic cursor per node; ell16[n][pos] = clique.
// blocks [FILL_BLOCKS, ..): in[bc][col] -> inP[g][col][j], j = bc%16 (64B line/col).
// Pack: 4 cols/thread, f32x4 NT loads (16B/lane), register transpose, plain
// stores (L2 write-combining merges the 16B pieces into full lines).

__global__ __launch_bounds__(256) void fill_pack(const int* __restrict__ node_ids,
                                                 const int* __restrict__ clique_ids,
                                                 int* __restrict__ counts,
                                                 unsigned short* __restrict__ ell16,
                                                 const float* __restrict__ in,
                                                 float* __restrict__ inP) {
    int b   = blockIdx.x;
    int tid = threadIdx.x;
    if (b < FILL_BLOCKS) {
        int e = b * 256 + tid;
        if (e < NEDGE) {
            int n   = node_ids[e];
            int pos = atomicAdd(&counts[n], 1);
            if (pos < ELLW) ell16[(size_t)n * ELLW + pos] = (unsigned short)clique_ids[e];
        }
    } else {
        int pb = b - FILL_BLOCKS;
        int g  = pb / PACK_BLOCKS_X;
        int c4 = (pb % PACK_BLOCKS_X) * 256 + tid;
        if (c4 < COL4) {
            f32x4 v[16];                           // v[j][ci] = in[g*16+j][4*c4+ci]
            #pragma unroll
            for (int j = 0; j < 16; ++j)
                v[j] = __builtin_nontemporal_load(
                    reinterpret_cast<const f32x4*>(in + (size_t)(g * 16 + j) * NCLIQ + 4 * c4));
            #pragma unroll
            for (int ci = 0; ci < 4; ++ci) {
                f32x4* line = reinterpret_cast<f32x4*>(
                    inP + ((size_t)g * NCLIQ + 4 * c4 + ci) * 16);
                #pragma unroll
                for (int q = 0; q < 4; ++q) {
                    f32x4 t = { v[4 * q + 0][ci], v[4 * q + 1][ci],
                                v[4 * q + 2][ci], v[4 * q + 3][ci] };
                    line[q] = t;
                }
            }
        }
    }
}

// ---------------- gather: 1 node x 1 plane-quad per thread, LDS-transposed stores ----
// Compute: wave = 16 nodes x 4 quads; 4 q-lanes of a node read consecutive 16B
// of the same 64B inP line (full line use), ELL words broadcast. 8 predicated
// loads issued back-to-back (no serial col->load chain).
// Store: acc -> LDS [64][17] (pad -> <=2-way bank alias, free), barrier, then
// one NT f32x4 store per thread: per wave 4 planes x 256B contiguous segments
// (R5-verified exact-write pattern). Per-XCD working set: inP slice 800KB +
// ell16 1.6MB + deg 200KB = 2.6MB < 4MB L2.

__global__ __launch_bounds__(256) void gather_ell(const float* __restrict__ inP,
                                                  const int* __restrict__ deg,
                                                  const unsigned short* __restrict__ ell16,
                                                  float* __restrict__ out) {
    __shared__ float lds[NODEB][17];
    int b     = blockIdx.x;
    int k     = b & 7;
    int r     = b >> 3;
    int nb    = r % NBLK;
    int phase = r / NBLK;
    int g     = phase * 8 + k;                  // 8 groups active device-wide
    int tid   = threadIdx.x;
    int s     = tid >> 2;                       // node-local 0..63
    int q     = tid & 3;                        // plane quad 0..3
    int n     = nb * NODEB + s;

    float4 a  = make_float4(0.f, 0.f, 0.f, 0.f);
    float4 a2 = make_float4(0.f, 0.f, 0.f, 0.f);
    if (n < NODES) {
        int d = deg[n];
        const uint4 e = *reinterpret_cast<const uint4*>(ell16 + (size_t)n * ELLW);
        unsigned cs[8] = { e.x & 0xFFFFu, e.x >> 16, e.y & 0xFFFFu, e.y >> 16,
                           e.z & 0xFFFFu, e.z >> 16, e.w & 0xFFFFu, e.w >> 16 };
        const float* __restrict__ gbase = inP + (size_t)g * NCLIQ * 16 + q * 4;
        #pragma unroll
        for (int i = 0; i < 8; i += 2) {
            if (i < d) {
                const float4 p = *reinterpret_cast<const float4*>(gbase + (size_t)cs[i] * 16);
                a.x += p.x; a.y += p.y; a.z += p.z; a.w += p.w;
            }
            if (i + 1 < d) {
                const float4 p = *reinterpret_cast<const float4*>(gbase + (size_t)cs[i + 1] * 16);
                a2.x += p.x; a2.y += p.y; a2.z += p.z; a2.w += p.w;
            }
        }
        if (d > 8) {                            // P(deg>8) ~ 0.1%: scalar tail
            for (int i = 8; i < d && i < ELLW; ++i) {
                unsigned col = ell16[(size_t)n * ELLW + i];
                const float4 p = *reinterpret_cast<const float4*>(gbase + (size_t)col * 16);
                a.x += p.x; a.y += p.y; a.z += p.z; a.w += p.w;
            }
        }
        a.x += a2.x; a.y += a2.y; a.z += a2.z; a.w += a2.w;
    }
    lds[s][q * 4 + 0] = a.x;                    // plane j = q*4+w of node s
    lds[s][q * 4 + 1] = a.y;
    lds[s][q * 4 + 2] = a.z;
    lds[s][q * 4 + 3] = a.w;
    __syncthreads();

    int p  = tid >> 4;                          // plane 0..15
    int i4 = (tid & 15) * 4;                    // node chunk 0..60
    int n0 = nb * NODEB + i4;
    if (n0 + 3 < NODES) {                       // NODES%4==0: no partial vec4
        f32x4 o = { lds[i4][p], lds[i4 + 1][p], lds[i4 + 2][p], lds[i4 + 3][p] };
        __builtin_nontemporal_store(o,
            reinterpret_cast<f32x4*>(out + (size_t)(g * 16 + p) * NODES + n0));
    }
}

// ---------------- launch ----------------

extern "C" void kernel_launch(void* const* d_in, const int* in_sizes, int n_in,
                              void* d_out, int out_size, void* d_ws, size_t ws_size,
                              hipStream_t stream) {
    const float* in         = (const float*)d_in[0];
    const int*   node_ids   = (const int*)d_in[1];
    const int*   clique_ids = (const int*)d_in[2];
    float*       out        = (float*)d_out;

    // ws layout: counts[50000] int | ell16[50000*16] ushort | inP[64*12500*16] float
    int*            counts = (int*)d_ws;
    unsigned short* ell16  = (unsigned short*)(counts + NODES);          // byte 200,000
    float*          inP    = (float*)((char*)d_ws + 200000 + 1600000);   // byte 1,800,000 (16B-aligned)

    zero_counts<<<(NODES / 4 + 255) / 256, 256, 0, stream>>>((int4*)counts);
    fill_pack<<<FILL_BLOCKS + PACK_BLOCKS, 256, 0, stream>>>(node_ids, clique_ids,
                                                             counts, ell16, in, inP);
    gather_ell<<<NGRP * NBLK, 256, 0, stream>>>(inP, counts, ell16, out);
}

// Round 8
// 94.284 us; speedup vs baseline: 1.9759x; 1.1068x over previous
//
#include <hip/hip_runtime.h>

// Problem constants (fixed by the reference setup):
// B=16, C=64, NC=12500, N=50000, K=8, E=NC*K=100000
#define NCLIQ  12500
#define NODES  50000
#define NEDGE  100000
#define NGRP   64                                  // 1024 bc / 16 per group
#define ELLW   16                                  // slots/node (dataset max deg <= 16, validated R5+)

#define FILL_BLOCKS   ((NEDGE + 255) / 256)        // 391
#define COL4          (NCLIQ / 4)                  // 3125 (NCLIQ % 4 == 0)
#define PACK_BLOCKS_X ((COL4 + 255) / 256)         // 13
#define PACK_BLOCKS   (PACK_BLOCKS_X * NGRP)       // 832

#define NODEB 64                                   // nodes per gather block
#define NBLK  ((NODES + NODEB - 1) / NODEB)        // 782

typedef float f32x4 __attribute__((ext_vector_type(4)));

// ---------------- zero degree counters ----------------

__global__ __launch_bounds__(256) void zero_counts(int4* __restrict__ counts4) {
    int t = blockIdx.x * 256 + threadIdx.x;
    if (t < NODES / 4) counts4[t] = make_int4(0, 0, 0, 0);
}

// ---------------- fused: ushort-ELL build + 16-bc input pack ----------------
// blocks [0, FILL_BLOCKS): pos = atomic cursor per node; ell16[n][pos] = clique.
// blocks [FILL_BLOCKS, ..): in[bc][col] -> inP[g][col][j], j = bc%16 (64B line/col).
// Pack loads are PLAIN (in stays L3-warm across timed replays); inP stores plain
// (gather wants it L2/L3-resident).

__global__ __launch_bounds__(256) void fill_pack(const int* __restrict__ node_ids,
                                                 const int* __restrict__ clique_ids,
                                                 int* __restrict__ counts,
                                                 unsigned short* __restrict__ ell16,
                                                 const float* __restrict__ in,
                                                 float* __restrict__ inP) {
    int b   = blockIdx.x;
    int tid = threadIdx.x;
    if (b < FILL_BLOCKS) {
        int e = b * 256 + tid;
        if (e < NEDGE) {
            int n   = node_ids[e];
            int pos = atomicAdd(&counts[n], 1);
            if (pos < ELLW) ell16[(size_t)n * ELLW + pos] = (unsigned short)clique_ids[e];
        }
    } else {
        int pb = b - FILL_BLOCKS;
        int g  = pb / PACK_BLOCKS_X;
        int c4 = (pb % PACK_BLOCKS_X) * 256 + tid;
        if (c4 < COL4) {
            f32x4 v[16];                           // v[j][ci] = in[g*16+j][4*c4+ci]
            #pragma unroll
            for (int j = 0; j < 16; ++j)
                v[j] = *reinterpret_cast<const f32x4*>(
                    in + (size_t)(g * 16 + j) * NCLIQ + 4 * c4);
            #pragma unroll
            for (int ci = 0; ci < 4; ++ci) {
                f32x4* line = reinterpret_cast<f32x4*>(
                    inP + ((size_t)g * NCLIQ + 4 * c4 + ci) * 16);
                #pragma unroll
                for (int q = 0; q < 4; ++q) {
                    f32x4 t = { v[4 * q + 0][ci], v[4 * q + 1][ci],
                                v[4 * q + 2][ci], v[4 * q + 3][ci] };
                    line[q] = t;
                }
            }
        }
    }
}

// ---------------- gather: 2 groups per block, 1 node x 1 plane-quad per thread ----
// Pair (gA, gB=gA+8) share one XCD phase: ELL uint4 + deg + 8 bfe decodes +
// addressing are paid ONCE and reused for both groups (the dominant fixed cost
// at avg degree 2). The two groups' inP loads are independent -> up to 16
// outstanding per thread. Per-XCD working set: 2 inP slices (1.6MB) + ell16
// (1.6MB) + deg (0.2MB) = 3.4MB < 4MB L2.
// Store: acc -> LDS [2][64][17] (pad: free), one barrier, then 2 NT f32x4
// stores per thread (4 planes x 256B contiguous per wave per group).

__global__ __launch_bounds__(256) void gather_ell(const float* __restrict__ inP,
                                                  const int* __restrict__ deg,
                                                  const unsigned short* __restrict__ ell16,
                                                  float* __restrict__ out) {
    __shared__ float lds[2][NODEB][17];
    int b     = blockIdx.x;                     // [0, (NGRP/2)*NBLK)
    int k     = b & 7;                          // XCD slot
    int r     = b >> 3;
    int nb    = r % NBLK;
    int pp    = r / NBLK;                       // pair-phase 0..3
    int gA    = pp * 16 + k;
    int gB    = gA + 8;
    int tid   = threadIdx.x;
    int s     = tid >> 2;                       // node-local 0..63
    int q     = tid & 3;                        // plane quad 0..3
    int n     = nb * NODEB + s;

    float4 aA = make_float4(0.f, 0.f, 0.f, 0.f);
    float4 aB = make_float4(0.f, 0.f, 0.f, 0.f);
    if (n < NODES) {
        int d = deg[n];
        const uint4 e = *reinterpret_cast<const uint4*>(ell16 + (size_t)n * ELLW);
        unsigned cs[8] = { e.x & 0xFFFFu, e.x >> 16, e.y & 0xFFFFu, e.y >> 16,
                           e.z & 0xFFFFu, e.z >> 16, e.w & 0xFFFFu, e.w >> 16 };
        const float* __restrict__ baseA = inP + (size_t)gA * NCLIQ * 16 + q * 4;
        const float* __restrict__ baseB = inP + (size_t)gB * NCLIQ * 16 + q * 4;
        #pragma unroll
        for (int i = 0; i < 8; ++i) {
            if (i < d) {
                size_t off = (size_t)cs[i] * 16;
                const float4 pA = *reinterpret_cast<const float4*>(baseA + off);
                const float4 pB = *reinterpret_cast<const float4*>(baseB + off);
                aA.x += pA.x; aA.y += pA.y; aA.z += pA.z; aA.w += pA.w;
                aB.x += pB.x; aB.y += pB.y; aB.z += pB.z; aB.w += pB.w;
            }
        }
        if (d > 8) {                            // P(deg>8) ~ 0.1%: scalar tail
            for (int i = 8; i < d && i < ELLW; ++i) {
                size_t off = (size_t)ell16[(size_t)n * ELLW + i] * 16;
                const float4 pA = *reinterpret_cast<const float4*>(baseA + off);
                const float4 pB = *reinterpret_cast<const float4*>(baseB + off);
                aA.x += pA.x; aA.y += pA.y; aA.z += pA.z; aA.w += pA.w;
                aB.x += pB.x; aB.y += pB.y; aB.z += pB.z; aB.w += pB.w;
            }
        }
    }
    lds[0][s][q * 4 + 0] = aA.x;  lds[0][s][q * 4 + 1] = aA.y;
    lds[0][s][q * 4 + 2] = aA.z;  lds[0][s][q * 4 + 3] = aA.w;
    lds[1][s][q * 4 + 0] = aB.x;  lds[1][s][q * 4 + 1] = aB.y;
    lds[1][s][q * 4 + 2] = aB.z;  lds[1][s][q * 4 + 3] = aB.w;
    __syncthreads();

    int p  = tid >> 4;                          // plane 0..15
    int i4 = (tid & 15) * 4;                    // node chunk base
    int n0 = nb * NODEB + i4;
    if (n0 + 3 < NODES) {                       // NODES%4==0: no partial vec4
        f32x4 oA = { lds[0][i4][p], lds[0][i4 + 1][p], lds[0][i4 + 2][p], lds[0][i4 + 3][p] };
        f32x4 oB = { lds[1][i4][p], lds[1][i4 + 1][p], lds[1][i4 + 2][p], lds[1][i4 + 3][p] };
        __builtin_nontemporal_store(oA,
            reinterpret_cast<f32x4*>(out + (size_t)(gA * 16 + p) * NODES + n0));
        __builtin_nontemporal_store(oB,
            reinterpret_cast<f32x4*>(out + (size_t)(gB * 16 + p) * NODES + n0));
    }
}

// ---------------- launch ----------------

extern "C" void kernel_launch(void* const* d_in, const int* in_sizes, int n_in,
                              void* d_out, int out_size, void* d_ws, size_t ws_size,
                              hipStream_t stream) {
    const float* in         = (const float*)d_in[0];
    const int*   node_ids   = (const int*)d_in[1];
    const int*   clique_ids = (const int*)d_in[2];
    float*       out        = (float*)d_out;

    // ws layout: counts[50000] int | ell16[50000*16] ushort | inP[64*12500*16] float
    int*            counts = (int*)d_ws;
    unsigned short* ell16  = (unsigned short*)(counts + NODES);          // byte 200,000
    float*          inP    = (float*)((char*)d_ws + 200000 + 1600000);   // byte 1,800,000 (16B-aligned)

    zero_counts<<<(NODES / 4 + 255) / 256, 256, 0, stream>>>((int4*)counts);
    fill_pack<<<FILL_BLOCKS + PACK_BLOCKS, 256, 0, stream>>>(node_ids, clique_ids,
                                                             counts, ell16, in, inP);
    gather_ell<<<(NGRP / 2) * NBLK, 256, 0, stream>>>(inP, counts, ell16, out);
}